// Round 8
// baseline (307.673 us; speedup 1.0000x reference)
//
#include <hip/hip_runtime.h>
#include <hip/hip_bf16.h>

// Problem geometry (fixed by the reference):
//   x: (B=16, C=64, S=512, S=512) fp32
//   out: (16, 64, 256, 256) fp32
//   out[b,c,ho,wo] = w[c] * mean(x[b,c,2ho:2ho+2,2wo:2wo+2]) + bias[c]

#define B_ 16
#define C_ 64
#define S_ 512
#define HO (S_ / 2)   // 256
#define WO (S_ / 2)   // 256

// Work unit = one output row-pair (2 output rows = 4 input rows).
//   per unit: read 8 KiB contiguous, write 2 KiB contiguous (per wave).
// Each wave owns CHUNK consecutive units -> streams 128 KiB contiguous reads.
// CHUNK=16 divides PAIRS_PER_CH=128, so a chunk never crosses a channel plane:
// channel/weight/bias/base-pointer math hoists out of the inner loop.
#define PAIRS_PER_CH  (HO / 2)                    // 128
#define PAIRS_TOTAL   (B_ * C_ * PAIRS_PER_CH)    // 131072
#define NUM_WAVES     8192                        // grid 2048 x 256 / 64
#define CHUNK         (PAIRS_TOTAL / NUM_WAVES)   // 16

typedef float f32x4 __attribute__((ext_vector_type(4)));

__global__ __launch_bounds__(256) void avgpool_affine_kernel(
    const float* __restrict__ x,
    const float* __restrict__ weight,
    const float* __restrict__ bias,
    float* __restrict__ out)
{
    const int lane = threadIdx.x & 63;
    const int wave = (blockIdx.x * blockDim.x + threadIdx.x) >> 6;

    const int u0 = wave * CHUNK;                  // first row-pair unit
    const int p0 = u0 & (PAIRS_PER_CH - 1);       // starting pair within plane
    const int bc = u0 >> 7;                       // b*C + c (constant per wave)
    const int c  = bc & (C_ - 1);

    const float w  = weight[c];
    const float bs = bias[c];

    const float* __restrict__ ip = x + (long long)bc * (S_ * S_)
                                 + (long long)(4 * p0) * S_ + 8 * lane;
    float* __restrict__ op = out + (long long)bc * (HO * WO)
                           + (long long)(2 * p0) * WO + 4 * lane;

#pragma unroll 2
    for (int it = 0; it < CHUNK; ++it)
    {
        const f32x4 a0 = __builtin_nontemporal_load(reinterpret_cast<const f32x4*>(ip));
        const f32x4 a1 = __builtin_nontemporal_load(reinterpret_cast<const f32x4*>(ip + 4));
        const f32x4 b0 = __builtin_nontemporal_load(reinterpret_cast<const f32x4*>(ip + S_));
        const f32x4 b1 = __builtin_nontemporal_load(reinterpret_cast<const f32x4*>(ip + S_ + 4));
        const f32x4 c0 = __builtin_nontemporal_load(reinterpret_cast<const f32x4*>(ip + 2 * S_));
        const f32x4 c1 = __builtin_nontemporal_load(reinterpret_cast<const f32x4*>(ip + 2 * S_ + 4));
        const f32x4 d0 = __builtin_nontemporal_load(reinterpret_cast<const f32x4*>(ip + 3 * S_));
        const f32x4 d1 = __builtin_nontemporal_load(reinterpret_cast<const f32x4*>(ip + 3 * S_ + 4));

        f32x4 o0, o1;
        o0.x = __builtin_fmaf(w, 0.25f * (a0.x + a0.y + b0.x + b0.y), bs);
        o0.y = __builtin_fmaf(w, 0.25f * (a0.z + a0.w + b0.z + b0.w), bs);
        o0.z = __builtin_fmaf(w, 0.25f * (a1.x + a1.y + b1.x + b1.y), bs);
        o0.w = __builtin_fmaf(w, 0.25f * (a1.z + a1.w + b1.z + b1.w), bs);
        o1.x = __builtin_fmaf(w, 0.25f * (c0.x + c0.y + d0.x + d0.y), bs);
        o1.y = __builtin_fmaf(w, 0.25f * (c0.z + c0.w + d0.z + d0.w), bs);
        o1.z = __builtin_fmaf(w, 0.25f * (c1.x + c1.y + d1.x + d1.y), bs);
        o1.w = __builtin_fmaf(w, 0.25f * (c1.z + c1.w + d1.z + d1.w), bs);

        __builtin_nontemporal_store(o0, reinterpret_cast<f32x4*>(op));
        __builtin_nontemporal_store(o1, reinterpret_cast<f32x4*>(op + WO));

        ip += 4 * S_;   // next 4 input rows
        op += 2 * WO;   // next 2 output rows
    }
}

extern "C" void kernel_launch(void* const* d_in, const int* in_sizes, int n_in,
                              void* d_out, int out_size, void* d_ws, size_t ws_size,
                              hipStream_t stream)
{
    const float* x      = (const float*)d_in[0];
    const float* weight = (const float*)d_in[1];
    const float* bias   = (const float*)d_in[2];
    float* out          = (float*)d_out;

    const int block = 256;   // 4 waves/block
    const int grid  = 2048;  // 8192 waves x 16 units each, exact cover
    avgpool_affine_kernel<<<grid, block, 0, stream>>>(x, weight, bias, out);
}

// Round 10
// 272.716 us; speedup vs baseline: 1.1282x; 1.1282x over previous
//
#include <hip/hip_runtime.h>
#include <hip/hip_bf16.h>

// Problem geometry (fixed by the reference):
//   x: (B=16, C=64, S=512, S=512) fp32
//   out: (16, 64, 256, 256) fp32
//   out[b,c,ho,wo] = w[c] * mean(x[b,c,2ho:2ho+2,2wo:2wo+2]) + bias[c]

#define B_ 16
#define C_ 64
#define S_ 512
#define HO (S_ / 2)   // 256
#define WO (S_ / 2)   // 256

// Work unit = one output row-pair (2 output rows = 4 input rows):
//   read 8 KiB contiguous, write 2 KiB contiguous per wave per unit.
// INTERLEAVED mapping (unit = wave + it*NUM_WAVES): concurrent waves touch
// consecutive 8 KiB blocks -> dense moving window over HBM, all channels hit
// uniformly (the chunked variant camped on one channel phase: 307 us vs 234).
// With NUM_WAVES=8192: p = wave&127 and c = wave>>7 are CONSTANT per wave
// (64*it & 63 == 0), b = it -> weight/bias/row math hoists; the iteration
// stride is exactly 64 channel planes for input and output alike.
#define PAIRS_PER_CH  (HO / 2)                    // 128
#define PAIRS_TOTAL   (B_ * C_ * PAIRS_PER_CH)    // 131072
#define NUM_WAVES     8192                        // grid 2048 x 256 / 64
#define ITERS         (PAIRS_TOTAL / NUM_WAVES)   // 16 (= B_: one image per it)

typedef float f32x4 __attribute__((ext_vector_type(4)));

__global__ __launch_bounds__(256) void avgpool_affine_kernel(
    const float* __restrict__ x,
    const float* __restrict__ weight,
    const float* __restrict__ bias,
    float* __restrict__ out)
{
    const int lane = threadIdx.x & 63;
    const int wave = (blockIdx.x * blockDim.x + threadIdx.x) >> 6;

    const int p = wave & (PAIRS_PER_CH - 1);      // pair row-index, constant
    const int c = wave >> 7;                      // channel, constant (0..63)

    const float w  = weight[c];
    const float bs = bias[c];

    const float* __restrict__ ip = x + (long long)c * (S_ * S_)
                                 + (long long)(4 * p) * S_ + 8 * lane;
    float* __restrict__ op = out + (long long)c * (HO * WO)
                           + (long long)(2 * p) * WO + 4 * lane;

#pragma unroll 2
    for (int it = 0; it < ITERS; ++it)
    {
        const f32x4 a0 = __builtin_nontemporal_load(reinterpret_cast<const f32x4*>(ip));
        const f32x4 a1 = __builtin_nontemporal_load(reinterpret_cast<const f32x4*>(ip + 4));
        const f32x4 b0 = __builtin_nontemporal_load(reinterpret_cast<const f32x4*>(ip + S_));
        const f32x4 b1 = __builtin_nontemporal_load(reinterpret_cast<const f32x4*>(ip + S_ + 4));
        const f32x4 c0 = __builtin_nontemporal_load(reinterpret_cast<const f32x4*>(ip + 2 * S_));
        const f32x4 c1 = __builtin_nontemporal_load(reinterpret_cast<const f32x4*>(ip + 2 * S_ + 4));
        const f32x4 d0 = __builtin_nontemporal_load(reinterpret_cast<const f32x4*>(ip + 3 * S_));
        const f32x4 d1 = __builtin_nontemporal_load(reinterpret_cast<const f32x4*>(ip + 3 * S_ + 4));

        f32x4 o0, o1;
        o0.x = __builtin_fmaf(w, 0.25f * (a0.x + a0.y + b0.x + b0.y), bs);
        o0.y = __builtin_fmaf(w, 0.25f * (a0.z + a0.w + b0.z + b0.w), bs);
        o0.z = __builtin_fmaf(w, 0.25f * (a1.x + a1.y + b1.x + b1.y), bs);
        o0.w = __builtin_fmaf(w, 0.25f * (a1.z + a1.w + b1.z + b1.w), bs);
        o1.x = __builtin_fmaf(w, 0.25f * (c0.x + c0.y + d0.x + d0.y), bs);
        o1.y = __builtin_fmaf(w, 0.25f * (c0.z + c0.w + d0.z + d0.w), bs);
        o1.z = __builtin_fmaf(w, 0.25f * (c1.x + c1.y + d1.x + d1.y), bs);
        o1.w = __builtin_fmaf(w, 0.25f * (c1.z + c1.w + d1.z + d1.w), bs);

        __builtin_nontemporal_store(o0, reinterpret_cast<f32x4*>(op));
        __builtin_nontemporal_store(o1, reinterpret_cast<f32x4*>(op + WO));

        ip += 64LL * S_ * S_;    // +64 input planes  (next image, same c)
        op += 64LL * HO * WO;    // +64 output planes
    }
}

extern "C" void kernel_launch(void* const* d_in, const int* in_sizes, int n_in,
                              void* d_out, int out_size, void* d_ws, size_t ws_size,
                              hipStream_t stream)
{
    const float* x      = (const float*)d_in[0];
    const float* weight = (const float*)d_in[1];
    const float* bias   = (const float*)d_in[2];
    float* out          = (float*)d_out;

    const int block = 256;   // 4 waves/block
    const int grid  = 2048;  // 8192 waves; interleaved cover, 16 its each
    avgpool_affine_kernel<<<grid, block, 0, stream>>>(x, weight, bias, out);
}

// Round 11
// 234.120 us; speedup vs baseline: 1.3142x; 1.1649x over previous
//
#include <hip/hip_runtime.h>
#include <hip/hip_bf16.h>

// Problem geometry (fixed by the reference):
//   x: (B=16, C=64, S=512, S=512) fp32
//   out: (16, 64, 256, 256) fp32
//   out[b,c,ho,wo] = w[c] * mean(x[b,c,2ho:2ho+2,2wo:2wo+2]) + bias[c]

#define B_ 16
#define C_ 64
#define S_ 512
#define HO (S_ / 2)   // 256
#define WO (S_ / 2)   // 256

// One wave iteration = 2 consecutive output rows (one "row-pair" unit):
//   reads input rows [4u, 4u+4) of a channel plane — contiguous 8 KiB/wave
//   writes output rows [2u, 2u+2)                 — contiguous 2 KiB/wave
// Lane i handles input cols [8i, 8i+8) (two float4 per row).
// Grid-stride over units: concurrent waves cover a dense moving window.
#define PAIRS_PER_CH  (HO / 2)                    // 128
#define PAIRS_TOTAL   (B_ * C_ * PAIRS_PER_CH)    // 131072

typedef float f32x4 __attribute__((ext_vector_type(4)));

__global__ __launch_bounds__(256) void avgpool_affine_kernel(
    const float* __restrict__ x,
    const float* __restrict__ weight,
    const float* __restrict__ bias,
    float* __restrict__ out)
{
    const int lane     = threadIdx.x & 63;
    const int wave     = (blockIdx.x * blockDim.x + threadIdx.x) >> 6;
    const int numWaves = (gridDim.x * blockDim.x) >> 6;

    for (int u = wave; u < PAIRS_TOTAL; u += numWaves)
    {
        const int p  = u & (PAIRS_PER_CH - 1);    // 0..127
        const int bc = u >> 7;                    // b*C + c
        const int c  = bc & (C_ - 1);

        const long long ibase = (long long)bc * (S_ * S_)
                              + (long long)(4 * p) * S_ + 8 * lane;

        // rows 4p, 4p+1 -> output row 2p
        const f32x4 a0 = __builtin_nontemporal_load(reinterpret_cast<const f32x4*>(x + ibase));
        const f32x4 a1 = __builtin_nontemporal_load(reinterpret_cast<const f32x4*>(x + ibase + 4));
        const f32x4 b0 = __builtin_nontemporal_load(reinterpret_cast<const f32x4*>(x + ibase + S_));
        const f32x4 b1 = __builtin_nontemporal_load(reinterpret_cast<const f32x4*>(x + ibase + S_ + 4));
        // rows 4p+2, 4p+3 -> output row 2p+1
        const f32x4 c0 = __builtin_nontemporal_load(reinterpret_cast<const f32x4*>(x + ibase + 2 * S_));
        const f32x4 c1 = __builtin_nontemporal_load(reinterpret_cast<const f32x4*>(x + ibase + 2 * S_ + 4));
        const f32x4 d0 = __builtin_nontemporal_load(reinterpret_cast<const f32x4*>(x + ibase + 3 * S_));
        const f32x4 d1 = __builtin_nontemporal_load(reinterpret_cast<const f32x4*>(x + ibase + 3 * S_ + 4));

        const float w  = weight[c];
        const float bs = bias[c];

        f32x4 o0, o1;
        o0.x = __builtin_fmaf(w, 0.25f * (a0.x + a0.y + b0.x + b0.y), bs);
        o0.y = __builtin_fmaf(w, 0.25f * (a0.z + a0.w + b0.z + b0.w), bs);
        o0.z = __builtin_fmaf(w, 0.25f * (a1.x + a1.y + b1.x + b1.y), bs);
        o0.w = __builtin_fmaf(w, 0.25f * (a1.z + a1.w + b1.z + b1.w), bs);
        o1.x = __builtin_fmaf(w, 0.25f * (c0.x + c0.y + d0.x + d0.y), bs);
        o1.y = __builtin_fmaf(w, 0.25f * (c0.z + c0.w + d0.z + d0.w), bs);
        o1.z = __builtin_fmaf(w, 0.25f * (c1.x + c1.y + d1.x + d1.y), bs);
        o1.w = __builtin_fmaf(w, 0.25f * (c1.z + c1.w + d1.z + d1.w), bs);

        const long long obase = (long long)bc * (HO * WO)
                              + (long long)(2 * p) * WO + 4 * lane;
        __builtin_nontemporal_store(o0, reinterpret_cast<f32x4*>(out + obase));
        __builtin_nontemporal_store(o1, reinterpret_cast<f32x4*>(out + obase + WO));
    }
}

extern "C" void kernel_launch(void* const* d_in, const int* in_sizes, int n_in,
                              void* d_out, int out_size, void* d_ws, size_t ws_size,
                              hipStream_t stream)
{
    const float* x      = (const float*)d_in[0];
    const float* weight = (const float*)d_in[1];
    const float* bias   = (const float*)d_in[2];
    float* out          = (float*)d_out;

    const int block = 256;   // 4 waves/block
    const int grid  = 2048;  // 8192 waves; 16 row-pair units per wave
    avgpool_affine_kernel<<<grid, block, 0, stream>>>(x, weight, bias, out);
}